// Round 3
// baseline (841.545 us; speedup 1.0000x reference)
//
#include <hip/hip_runtime.h>
#include <hip/hip_bf16.h>

#define ROW_LEN 2048
#define WAVES_PER_BLOCK 4
// 8 int4 vectors per lane: 8 * 4 elems * 64 lanes = 2048 elems = one row
#define VECS 8

__global__ __launch_bounds__(256, 4)
void Custom_Softmax_48395691491529_kernel(const int* __restrict__ xq,
                                          const float* __restrict__ scale_p,
                                          float* __restrict__ out,
                                          int rows, long long n_elems)
{
    const int lane = (int)(threadIdx.x & 63u);
    const int wave = (int)(threadIdx.x >> 6u);
    const int row  = blockIdx.x * WAVES_PER_BLOCK + wave;

    // Output 1 of the tuple: the fixed requant scale, as float32.
    // d_out is float* (ref outputs are int8 + float32 -> "else float*").
    if (blockIdx.x == 0 && threadIdx.x == 0)
        out[n_elems] = 0.1f;

    if (row >= rows) return;  // wave-uniform branch

    const float scale = *scale_p;                      // uniform load
    const float c = scale * 1.4426950408889634f;       // scale * log2(e)

    const long long base = (long long)row * ROW_LEN;
    const int4* __restrict__ src = (const int4*)(xq + base);

    // --- load: 8 coalesced int4 per lane (wave covers 1024B per vector) ---
    int4 q[VECS];
#pragma unroll
    for (int it = 0; it < VECS; ++it)
        q[it] = src[it * 64 + lane];

    // --- row max (stable softmax) ---
    int m = q[0].x;
#pragma unroll
    for (int it = 0; it < VECS; ++it) {
        m = max(m, q[it].x); m = max(m, q[it].y);
        m = max(m, q[it].z); m = max(m, q[it].w);
    }
#pragma unroll
    for (int off = 1; off < 64; off <<= 1)
        m = max(m, __shfl_xor(m, off));

    // --- exp2((q-m)*scale*log2e) -> v_exp_f32; accumulate sum ---
    float e[VECS][4];
    float s = 0.0f;
#pragma unroll
    for (int it = 0; it < VECS; ++it) {
        e[it][0] = exp2f((float)(q[it].x - m) * c);
        e[it][1] = exp2f((float)(q[it].y - m) * c);
        e[it][2] = exp2f((float)(q[it].z - m) * c);
        e[it][3] = exp2f((float)(q[it].w - m) * c);
        s += e[it][0] + e[it][1] + e[it][2] + e[it][3];
    }
#pragma unroll
    for (int off = 1; off < 64; off <<= 1)
        s += __shfl_xor(s, off);

    // y_q = clip(round((e/s)/0.1), -128, 127); e/s/0.1 = e * (10/s), >= 0
    const float inv = 10.0f / s;

#pragma unroll
    for (int it = 0; it < VECS; ++it) {
        float4 o;
        o.x = fminf(rintf(e[it][0] * inv), 127.0f);  // v_rndne: half-to-even == jnp.round
        o.y = fminf(rintf(e[it][1] * inv), 127.0f);  // values >= 0: upper clamp only
        o.z = fminf(rintf(e[it][2] * inv), 127.0f);
        o.w = fminf(rintf(e[it][3] * inv), 127.0f);
        // 4 consecutive f32 = 16B store, wave writes 1KiB contiguous
        *(float4*)(out + base + it * 256 + lane * 4) = o;
    }
}

extern "C" void kernel_launch(void* const* d_in, const int* in_sizes, int n_in,
                              void* d_out, int out_size, void* d_ws, size_t ws_size,
                              hipStream_t stream)
{
    const int*   xq      = (const int*)d_in[0];
    const float* scale_p = (const float*)d_in[1];
    float*       out     = (float*)d_out;

    const long long n = (long long)in_sizes[0];      // 134,217,728 elements
    const int rows    = (int)(n / ROW_LEN);          // 65,536 rows
    const int blocks  = (rows + WAVES_PER_BLOCK - 1) / WAVES_PER_BLOCK;

    hipLaunchKernelGGL(Custom_Softmax_48395691491529_kernel,
                       dim3(blocks), dim3(256), 0, stream,
                       xq, scale_p, out, rows, n);
}